// Round 1
// baseline (27283.820 us; speedup 1.0000x reference)
//
#include <hip/hip_runtime.h>
#include <math.h>

#define N_ROWS 8192
#define DIM 768
#define M_CB 64
#define K_CB 256
#define SUBDIM 12
#define H1 8192
#define H2 16384
#define LN_EPS 1e-5f

// ---------------------------------------------------------------------------
// Kernel 1: LayerNorm.  One block (256 threads) per row of x (768 cols).
// ---------------------------------------------------------------------------
__global__ __launch_bounds__(256) void k_layernorm(
    const float* __restrict__ x, const float* __restrict__ gamma,
    const float* __restrict__ beta, float* __restrict__ xn) {
  __shared__ float sbuf[8];
  int n = blockIdx.x;
  int t = threadIdx.x;
  const float* row = x + (size_t)n * DIM;
  float v0 = row[t], v1 = row[t + 256], v2 = row[t + 512];
  float s = v0 + v1 + v2;
#pragma unroll
  for (int o = 32; o > 0; o >>= 1) s += __shfl_down(s, o);
  if ((t & 63) == 0) sbuf[t >> 6] = s;
  __syncthreads();
  float mean = (sbuf[0] + sbuf[1] + sbuf[2] + sbuf[3]) * (1.0f / 768.0f);
  float d0 = v0 - mean, d1 = v1 - mean, d2 = v2 - mean;
  float q = d0 * d0 + d1 * d1 + d2 * d2;
#pragma unroll
  for (int o = 32; o > 0; o >>= 1) q += __shfl_down(q, o);
  if ((t & 63) == 0) sbuf[4 + (t >> 6)] = q;
  __syncthreads();
  float var = (sbuf[4] + sbuf[5] + sbuf[6] + sbuf[7]) * (1.0f / 768.0f);
  float rstd = 1.0f / sqrtf(var + LN_EPS);
  float* orow = xn + (size_t)n * DIM;
  orow[t]       = d0 * rstd * gamma[t]       + beta[t];
  orow[t + 256] = d1 * rstd * gamma[t + 256] + beta[t + 256];
  orow[t + 512] = d2 * rstd * gamma[t + 512] + beta[t + 512];
}

// ---------------------------------------------------------------------------
// Kernel 2: PQ argmin over K=256 codewords per (n, m).  One wave per (n, m),
// 4 waves per block.  fp contraction OFF + numpy pairwise-sum order so dist
// matches the np reference to ~1 ulp (argmin flips are the failure mode).
// ---------------------------------------------------------------------------
__global__ __launch_bounds__(256) void k_pq_argmin(
    const float* __restrict__ x, const float* __restrict__ cb,
    int* __restrict__ kmin) {
#pragma clang fp contract(off)
  int n = blockIdx.x;
  int wave = threadIdx.x >> 6;
  int lane = threadIdx.x & 63;
  int m = blockIdx.y * 4 + wave;
  const float* xr = x + (size_t)n * DIM + m * SUBDIM;
  float xv[SUBDIM];
#pragma unroll
  for (int d = 0; d < SUBDIM; d++) xv[d] = xr[d];
  float p[SUBDIM];
#pragma unroll
  for (int d = 0; d < SUBDIM; d++) p[d] = xv[d] * xv[d];
  // numpy pairwise_sum order for n=12: 8-leaf tree, then sequential tail
  float xsq = ((p[0] + p[1]) + (p[2] + p[3])) + ((p[4] + p[5]) + (p[6] + p[7]));
  xsq = xsq + p[8]; xsq = xsq + p[9]; xsq = xsq + p[10]; xsq = xsq + p[11];

  float bestv = INFINITY;
  int besti = 0;
#pragma unroll
  for (int j = 0; j < 4; j++) {
    int k = lane + 64 * j;
    const float* cv = cb + ((size_t)m * K_CB + k) * SUBDIM;
    float c[SUBDIM];
#pragma unroll
    for (int d = 0; d < SUBDIM; d++) c[d] = cv[d];
    float q[SUBDIM];
#pragma unroll
    for (int d = 0; d < SUBDIM; d++) q[d] = c[d] * c[d];
    float csq = ((q[0] + q[1]) + (q[2] + q[3])) + ((q[4] + q[5]) + (q[6] + q[7]));
    csq = csq + q[8]; csq = csq + q[9]; csq = csq + q[10]; csq = csq + q[11];
    float cr = 0.0f;  // einsum: sequential, no fma
#pragma unroll
    for (int d = 0; d < SUBDIM; d++) cr = cr + xv[d] * c[d];
    float dist = (xsq + csq) - 2.0f * cr;
    if (dist < bestv) { bestv = dist; besti = k; }  // ascending k: strict <
  }
#pragma unroll
  for (int o = 32; o > 0; o >>= 1) {
    float ov = __shfl_down(bestv, o);
    int oi = __shfl_down(besti, o);
    if (ov < bestv || (ov == bestv && oi < besti)) { bestv = ov; besti = oi; }
  }
  if (lane == 0) kmin[(size_t)n * M_CB + m] = besti;
}

// ---------------------------------------------------------------------------
// Kernel 3: h = tanh(xn @ W1 + b1).  fp32 tiled GEMM 128x128, BK=16,
// 256 threads, 8x8 per thread.
// ---------------------------------------------------------------------------
__global__ __launch_bounds__(256) void k_gemm1_tanh(
    const float* __restrict__ A, const float* __restrict__ B,
    const float* __restrict__ bias, float* __restrict__ C) {
  __shared__ float As[16][132];
  __shared__ float Bs[16][132];
  int tid = threadIdx.x;
  int rowBase = blockIdx.x * 128;
  int colBase = blockIdx.y * 128;
  int tx = tid & 15, ty = tid >> 4;
  int ar = tid >> 2;         // 0..63  (rows ar, ar+64)
  int ac = (tid & 3) * 4;    // 0,4,8,12
  int br = tid >> 5;         // 0..7   (rows br, br+8)
  int bc = (tid & 31) * 4;
  float acc[8][8] = {};
  const float* Aptr0 = A + (size_t)(rowBase + ar) * DIM + ac;
  const float* Aptr1 = A + (size_t)(rowBase + ar + 64) * DIM + ac;
  const float* Bptr0 = B + (size_t)br * H1 + colBase + bc;
  const float* Bptr1 = B + (size_t)(br + 8) * H1 + colBase + bc;
  for (int k0 = 0; k0 < DIM; k0 += 16) {
    float4 a0 = *(const float4*)(Aptr0 + k0);
    float4 a1 = *(const float4*)(Aptr1 + k0);
    float4 b0 = *(const float4*)(Bptr0 + (size_t)k0 * H1);
    float4 b1 = *(const float4*)(Bptr1 + (size_t)k0 * H1);
    __syncthreads();
    As[ac + 0][ar] = a0.x; As[ac + 1][ar] = a0.y;
    As[ac + 2][ar] = a0.z; As[ac + 3][ar] = a0.w;
    As[ac + 0][ar + 64] = a1.x; As[ac + 1][ar + 64] = a1.y;
    As[ac + 2][ar + 64] = a1.z; As[ac + 3][ar + 64] = a1.w;
    *(float4*)&Bs[br][bc] = b0;
    *(float4*)&Bs[br + 8][bc] = b1;
    __syncthreads();
#pragma unroll
    for (int kk = 0; kk < 16; kk++) {
      float av[8], bv[8];
      *(float4*)&av[0] = *(const float4*)&As[kk][ty * 8];
      *(float4*)&av[4] = *(const float4*)&As[kk][ty * 8 + 4];
      *(float4*)&bv[0] = *(const float4*)&Bs[kk][tx * 8];
      *(float4*)&bv[4] = *(const float4*)&Bs[kk][tx * 8 + 4];
#pragma unroll
      for (int i = 0; i < 8; i++)
#pragma unroll
        for (int j = 0; j < 8; j++)
          acc[i][j] = fmaf(av[i], bv[j], acc[i][j]);
    }
  }
  float bcol[8];
#pragma unroll
  for (int j = 0; j < 8; j++) bcol[j] = bias[colBase + tx * 8 + j];
#pragma unroll
  for (int i = 0; i < 8; i++) {
    int r = rowBase + ty * 8 + i;
    float4 o0, o1;
    o0.x = tanhf(acc[i][0] + bcol[0]); o0.y = tanhf(acc[i][1] + bcol[1]);
    o0.z = tanhf(acc[i][2] + bcol[2]); o0.w = tanhf(acc[i][3] + bcol[3]);
    o1.x = tanhf(acc[i][4] + bcol[4]); o1.y = tanhf(acc[i][5] + bcol[5]);
    o1.z = tanhf(acc[i][6] + bcol[6]); o1.w = tanhf(acc[i][7] + bcol[7]);
    float* crow = C + (size_t)r * H1 + colBase + tx * 8;
    *(float4*)(crow) = o0;
    *(float4*)(crow + 4) = o1;
  }
}

// ---------------------------------------------------------------------------
// Kernel 4: GEMM2 (h @ W2 + b2) with fused relu/interp/spike/gumbel/argmax/
// one-hot write.  Tile 128 rows x 256 cols (exactly one m-group), BK=16,
// 512 threads, 8x8 per thread.  Never materializes `a`.
// ---------------------------------------------------------------------------
__global__ __launch_bounds__(512) void k_gemm2_fused(
    const float* __restrict__ A, const float* __restrict__ B,
    const float* __restrict__ bias, const int* __restrict__ kmin,
    const float* __restrict__ interp_p, const float* __restrict__ gumbel,
    float* __restrict__ out) {
  __shared__ float As[16][132];
  __shared__ float Bs[16][260];
  __shared__ float redV[128][32];
  __shared__ int redI[128][32];
  __shared__ int bestk[128];
  int tid = threadIdx.x;
  int rowBase = blockIdx.x * 128;
  int m = blockIdx.y;
  int tx = tid & 31, ty = tid >> 5;  // 32 x 16 thread grid
  int ar = tid >> 2;                 // 0..127
  int ac = (tid & 3) * 4;
  int br = tid >> 6;                 // 0..7 (rows br, br+8)
  int bc = (tid & 63) * 4;
  float acc[8][8] = {};
  const float* Aptr = A + (size_t)(rowBase + ar) * H1 + ac;
  const float* Bptr0 = B + (size_t)br * H2 + m * K_CB + bc;
  const float* Bptr1 = B + (size_t)(br + 8) * H2 + m * K_CB + bc;
  for (int k0 = 0; k0 < H1; k0 += 16) {
    float4 a0 = *(const float4*)(Aptr + k0);
    float4 b0 = *(const float4*)(Bptr0 + (size_t)k0 * H2);
    float4 b1 = *(const float4*)(Bptr1 + (size_t)k0 * H2);
    __syncthreads();
    As[ac + 0][ar] = a0.x; As[ac + 1][ar] = a0.y;
    As[ac + 2][ar] = a0.z; As[ac + 3][ar] = a0.w;
    *(float4*)&Bs[br][bc] = b0;
    *(float4*)&Bs[br + 8][bc] = b1;
    __syncthreads();
#pragma unroll
    for (int kk = 0; kk < 16; kk++) {
      float av[8], bv[8];
      *(float4*)&av[0] = *(const float4*)&As[kk][ty * 8];
      *(float4*)&av[4] = *(const float4*)&As[kk][ty * 8 + 4];
      *(float4*)&bv[0] = *(const float4*)&Bs[kk][tx * 8];
      *(float4*)&bv[4] = *(const float4*)&Bs[kk][tx * 8 + 4];
#pragma unroll
      for (int i = 0; i < 8; i++)
#pragma unroll
        for (int j = 0; j < 8; j++)
          acc[i][j] = fmaf(av[i], bv[j], acc[i][j]);
    }
  }
  // ---- fused epilogue ----
  float interp = 1.0f / (1.0f + expf(-interp_p[0]));
  float w_a = 1.0f - interp;
  float spike = interp * 100.0f;
#pragma unroll
  for (int i = 0; i < 8; i++) {
    int r = ty * 8 + i;  // local row
    int n = rowBase + r;
    int kb = kmin[(size_t)n * M_CB + m];
    const float* grow = gumbel + ((size_t)n * M_CB + m) * K_CB;
    float bv = -INFINITY;
    int bi = 0;
#pragma unroll
    for (int j = 0; j < 8; j++) {
      int c = tx * 8 + j;
      float a = fmaxf(acc[i][j] + bias[m * K_CB + c], 0.0f);
      float l = w_a * a;
      if (c == kb) l += spike;
      l += grow[c];
      if (l > bv) { bv = l; bi = c; }  // ascending c: strict > keeps first
    }
    redV[r][tx] = bv;
    redI[r][tx] = bi;
  }
  __syncthreads();
  if (tid < 128) {
    float bv = redV[tid][0];
    int bi = redI[tid][0];
    for (int t2 = 1; t2 < 32; t2++) {
      float v = redV[tid][t2];
      int i2 = redI[tid][t2];
      if (v > bv || (v == bv && i2 < bi)) { bv = v; bi = i2; }
    }
    bestk[tid] = bi;
  }
  __syncthreads();
#pragma unroll
  for (int j = 0; j < 16; j++) {
    int pos = j * 512 + tid;     // 0..8191 float4 slots of the 128x256 tile
    int r = pos >> 6;            // 64 float4 per row
    int c = (pos & 63) * 4;
    int kb = bestk[r];
    float4 v;
    v.x = (c + 0 == kb) ? 1.0f : 0.0f;
    v.y = (c + 1 == kb) ? 1.0f : 0.0f;
    v.z = (c + 2 == kb) ? 1.0f : 0.0f;
    v.w = (c + 3 == kb) ? 1.0f : 0.0f;
    *(float4*)(out + ((size_t)(rowBase + r) * M_CB + m) * K_CB + c) = v;
  }
}

// ---------------------------------------------------------------------------
extern "C" void kernel_launch(void* const* d_in, const int* in_sizes, int n_in,
                              void* d_out, int out_size, void* d_ws,
                              size_t ws_size, hipStream_t stream) {
  (void)in_sizes; (void)n_in; (void)out_size; (void)ws_size;
  const float* x    = (const float*)d_in[0];
  const float* cb   = (const float*)d_in[1];
  const float* g    = (const float*)d_in[2];
  const float* be   = (const float*)d_in[3];
  const float* W1   = (const float*)d_in[4];
  const float* b1   = (const float*)d_in[5];
  const float* W2   = (const float*)d_in[6];
  const float* b2   = (const float*)d_in[7];
  const float* ip   = (const float*)d_in[8];
  const float* gum  = (const float*)d_in[9];
  float* out = (float*)d_out;

  char* ws = (char*)d_ws;
  float* xn  = (float*)(ws);                                  // 25,165,824 B
  float* h   = (float*)(ws + 25165824);                       // 268,435,456 B
  int*   kmn = (int*)(ws + 25165824 + 268435456);             // 2,097,152 B

  k_layernorm<<<N_ROWS, 256, 0, stream>>>(x, g, be, xn);
  k_pq_argmin<<<dim3(N_ROWS, 16), 256, 0, stream>>>(x, cb, kmn);
  k_gemm1_tanh<<<dim3(64, 64), 256, 0, stream>>>(xn, W1, b1, h);
  k_gemm2_fused<<<dim3(64, 64), 512, 0, stream>>>(h, W2, b2, kmn, ip, gum, out);
}